// Round 6
// baseline (91.163 us; speedup 1.0000x reference)
//
#include <hip/hip_runtime.h>
#include <hip/hip_bf16.h>

typedef __attribute__((ext_vector_type(8))) short short8;
typedef __attribute__((ext_vector_type(4))) float f32x4;

#define NROW 8192
#define DIM 512
#define BHALF 4096
#define NB2 32           // number of 256-row blocks
#define BT 256           // tile size
#define BK 32            // K-step (32 elems = 64 B rows -> conflict-free b128 reads)
#define NPAIR2 528       // NB2*(NB2+1)/2
#define XCHUNK2 66       // 528/8

__device__ __forceinline__ void gload_lds16(const void* g, void* l) {
  __builtin_amdgcn_global_load_lds(
      (const __attribute__((address_space(1))) void*)g,
      (__attribute__((address_space(3))) void*)l,
      16, 0, 0);
}

// ---------------- Kernel 1: row L2-normalize fp32 -> bf16 (wave per row) ----------------
__global__ __launch_bounds__(256) void normalize_kernel(const float* __restrict__ in,
                                                        __hip_bfloat16* __restrict__ out) {
  const int w = threadIdx.x >> 6, lane = threadIdx.x & 63;
  const int row = blockIdx.x * 4 + w;
  const float4* src = (const float4*)(in + (size_t)row * DIM) + lane * 2;
  const float4 v0 = src[0], v1 = src[1];
  float ss = v0.x * v0.x + v0.y * v0.y + v0.z * v0.z + v0.w * v0.w
           + v1.x * v1.x + v1.y * v1.y + v1.z * v1.z + v1.w * v1.w;
  #pragma unroll
  for (int m = 1; m < 64; m <<= 1) ss += __shfl_xor(ss, m);
  const float inv = 1.0f / fmaxf(sqrtf(ss), 1e-12f);
  __hip_bfloat16 o[8];
  o[0] = __float2bfloat16(v0.x * inv); o[1] = __float2bfloat16(v0.y * inv);
  o[2] = __float2bfloat16(v0.z * inv); o[3] = __float2bfloat16(v0.w * inv);
  o[4] = __float2bfloat16(v1.x * inv); o[5] = __float2bfloat16(v1.y * inv);
  o[6] = __float2bfloat16(v1.z * inv); o[7] = __float2bfloat16(v1.w * inv);
  *(short8*)(out + (size_t)row * DIM + lane * 8) = *(const short8*)o;
}

// ---------------- Kernel 2: symmetric 256x256 pair-tile Gram + exp-sums ----------------
// 528 blocks, one per (ib<=jb) pair of 256-row blocks. 512 threads = 8 waves
// (2 row-halves x 4 col-quarters); per-wave output 128x64 = 8x4 frags of 16x16x32.
// BK=32, 4-slot LDS ring (4 x 32KB), counted-vmcnt pipeline (T4): iteration t
// stages K-tile t+2 (slot free since t-2), computes tile t, then
// s_waitcnt vmcnt(4) (tile t+1 landed, t+2 in flight) + raw s_barrier.
// vmcnt NEVER drains to 0 in the main loop. T5 setprio around MFMA cluster.
__global__ __launch_bounds__(512, 2) void pair_gram_kernel(const __hip_bfloat16* __restrict__ f,
                                                           float* __restrict__ psum,
                                                           float* __restrict__ ppos) {
  __shared__ __align__(16) char lds[4][32768];   // ring: per slot A[256][32] | B[256][32]

  // --- XCD swizzle + 8x8 macro-tiled triangular pair decode (scalar-uniform) ---
  const int bid = blockIdx.x;
  const int wg = (bid & 7) * XCHUNK2 + (bid >> 3);
  int rem = wg, MI = 0, MJ = 0;
  {
    bool brk = false;
    for (MI = 0; MI < 4 && !brk; ++MI) {
      for (MJ = MI; MJ < 4; ++MJ) {
        const int sz = (MI == MJ) ? 36 : 64;
        if (rem < sz) { brk = true; break; }
        rem -= sz;
      }
    }
    if (brk) --MI;
  }
  int ib, jb;
  if (MI == MJ) {          // 8x8 triangle: 36 entries
    int i = 0, b = 0;
    while (b + (8 - i) <= rem) { b += 8 - i; ++i; }
    ib = MI * 8 + i; jb = MI * 8 + i + (rem - b);
  } else {
    ib = MI * 8 + (rem >> 3); jb = MJ * 8 + (rem & 7);
  }

  const int tid = threadIdx.x;
  const int lane = tid & 63;
  const int w = tid >> 6;            // wave 0..7
  const int wm = w >> 2;             // row half (0/1): rows wm*128..+128
  const int wn = w & 3;              // col quarter: cols wn*64..+64
  const int fr = lane & 15;          // fragment row/col index
  const int g = lane >> 4;           // k-group / C-row group

  // staging: thread t covers row tid>>2 (sweep q adds 128), 16B chunk (tid&3)
  const __hip_bfloat16* gA = f + (size_t)(ib * BT + (tid >> 2)) * DIM + (tid & 3) * 8;
  const __hip_bfloat16* gB = f + (size_t)(jb * BT + (tid >> 2)) * DIM + (tid & 3) * 8;
  char* ldsraw = (char*)lds;

  f32x4 acc[8][4];
  const f32x4 zero = {0.f, 0.f, 0.f, 0.f};
  #pragma unroll
  for (int mi = 0; mi < 8; ++mi)
    #pragma unroll
    for (int ni = 0; ni < 4; ++ni) acc[mi][ni] = zero;

  #define STAGE(buf, k0)                                                      \
    {                                                                         \
      char* dA = ldsraw + (buf) * 32768 + w * 1024;                           \
      char* dB = dA + 16384;                                                  \
      gload_lds16(gA + (k0), dA);                                             \
      gload_lds16(gA + (k0) + (size_t)128 * DIM, dA + 8192);                  \
      gload_lds16(gB + (k0), dB);                                             \
      gload_lds16(gB + (k0) + (size_t)128 * DIM, dB + 8192);                  \
    }

  // prologue: prime 2 K-tiles; wait only the first (counted)
  STAGE(0, 0);
  STAGE(1, BK);
  asm volatile("s_waitcnt vmcnt(4)" ::: "memory");
  __builtin_amdgcn_s_barrier();

  // per-lane fragment read offsets (linear LDS, conflict-free at 64B row stride)
  const int aoff = (wm * 128 + fr) * 64 + g * 16;           // + mi*1024
  const int boff = 16384 + (wn * 64 + fr) * 64 + g * 16;    // + ni*1024

  #pragma unroll 1
  for (int t = 0; t < 16; ++t) {
    if (t < 14) STAGE((t + 2) & 3, (t + 2) * BK);   // slot last read at t-2: free

    const char* base = ldsraw + (t & 3) * 32768;
    short8 aF[8], bF[4];
    #pragma unroll
    for (int mi = 0; mi < 8; ++mi) aF[mi] = *(const short8*)(base + aoff + mi * 1024);
    #pragma unroll
    for (int ni = 0; ni < 4; ++ni) bF[ni] = *(const short8*)(base + boff + ni * 1024);

    __builtin_amdgcn_s_setprio(1);
    #pragma unroll
    for (int mi = 0; mi < 8; ++mi)
      #pragma unroll
      for (int ni = 0; ni < 4; ++ni)
        acc[mi][ni] = __builtin_amdgcn_mfma_f32_16x16x32_bf16(aF[mi], bF[ni], acc[mi][ni], 0, 0, 0);
    __builtin_amdgcn_s_setprio(0);

    if (t < 15) {
      if (t < 14) asm volatile("s_waitcnt vmcnt(4)" ::: "memory");  // t+1 landed, t+2 in flight
      else        asm volatile("s_waitcnt vmcnt(0)" ::: "memory");  // tail: last tile
      __builtin_amdgcn_s_barrier();
    }
  }
  #undef STAGE

  // ---- epilogue: exp, row-sums (rows of ib) + col-sums (rows of jb), pos-pair ----
  __syncthreads();
  float* sc = (float*)ldsraw;   // rS[wn][256]@0, rP@1024, cS[wm][256]@2048, cP@2560
  float csum[4] = {0.f, 0.f, 0.f, 0.f}, pcol[4] = {0.f, 0.f, 0.f, 0.f};

  #pragma unroll
  for (int mi = 0; mi < 8; ++mi) {
    float rs4[4] = {0.f, 0.f, 0.f, 0.f}, pp4[4] = {0.f, 0.f, 0.f, 0.f};
    #pragma unroll
    for (int ni = 0; ni < 4; ++ni) {
      const int gcol = jb * BT + wn * 64 + ni * 16 + fr;
      #pragma unroll
      for (int r = 0; r < 4; ++r) {
        const int grow = ib * BT + wm * 128 + mi * 16 + g * 4 + r;
        const float dot = acc[mi][ni][r];
        const float e = (gcol == grow) ? 0.f : __expf((dot - 1.0f) * 10.0f);
        const float pos = (gcol == (grow ^ BHALF)) ? dot : 0.f;
        rs4[r] += e;  pp4[r] += pos;
        csum[ni] += e;  pcol[ni] += pos;
      }
    }
    #pragma unroll
    for (int r = 0; r < 4; ++r) {
      float a = rs4[r], b = pp4[r];
      #pragma unroll
      for (int msk = 1; msk < 16; msk <<= 1) { a += __shfl_xor(a, msk); b += __shfl_xor(b, msk); }
      rs4[r] = a; pp4[r] = b;
    }
    if (fr == 0) {
      #pragma unroll
      for (int r = 0; r < 4; ++r) {
        const int row = wm * 128 + mi * 16 + g * 4 + r;
        sc[wn * 256 + row]        = rs4[r];
        sc[1024 + wn * 256 + row] = pp4[r];
      }
    }
  }
  #pragma unroll
  for (int ni = 0; ni < 4; ++ni) {
    float a = csum[ni], b = pcol[ni];
    a += __shfl_xor(a, 16); b += __shfl_xor(b, 16);
    a += __shfl_xor(a, 32); b += __shfl_xor(b, 32);
    if (g == 0) {
      const int col = wn * 64 + ni * 16 + fr;
      sc[2048 + wm * 256 + col] = a;
      sc[2560 + wm * 256 + col] = b;
    }
  }
  __syncthreads();

  if (tid < 256) {                     // rows of block ib -> slot jb
    const int row = tid;
    const float s = sc[row] + sc[256 + row] + sc[512 + row] + sc[768 + row];
    const float p = sc[1024 + row] + sc[1280 + row] + sc[1536 + row] + sc[1792 + row];
    psum[(size_t)jb * NROW + ib * BT + row] = s;
    ppos[(size_t)jb * NROW + ib * BT + row] = p;
  } else if (ib != jb) {               // rows of block jb -> slot ib (transpose side)
    const int col = tid - 256;
    const float s = sc[2048 + col] + sc[2304 + col];
    const float p = sc[2560 + col] + sc[2816 + col];
    psum[(size_t)ib * NROW + jb * BT + col] = s;
    ppos[(size_t)ib * NROW + jb * BT + col] = p;
  }
}

// ---------------- Kernel 3a: per-row loss, 64 partials ----------------
__global__ __launch_bounds__(128) void loss_stage1(const float* __restrict__ psum,
                                                   const float* __restrict__ ppos,
                                                   float* __restrict__ partial) {
  const int row = blockIdx.x * 128 + threadIdx.x;
  float s = 0.f, p = 0.f;
  #pragma unroll 8
  for (int sl = 0; sl < NB2; ++sl) {
    s += psum[(size_t)sl * NROW + row];
    p += ppos[(size_t)sl * NROW + row];
  }
  float local = logf(s) + 10.0f - 10.0f * p;
  #pragma unroll
  for (int m = 1; m < 64; m <<= 1) local += __shfl_xor(local, m);
  __shared__ float red[2];
  if ((threadIdx.x & 63) == 0) red[threadIdx.x >> 6] = local;
  __syncthreads();
  if (threadIdx.x == 0) partial[blockIdx.x] = red[0] + red[1];
}

// ---------------- Kernel 3b: final scalar ----------------
__global__ __launch_bounds__(64) void loss_stage2(const float* __restrict__ partial,
                                                  float* __restrict__ out) {
  float v = partial[threadIdx.x];
  #pragma unroll
  for (int m = 1; m < 64; m <<= 1) v += __shfl_xor(v, m);
  if (threadIdx.x == 0) out[0] = v * (1.0f / (float)BHALF);
}

extern "C" void kernel_launch(void* const* d_in, const int* in_sizes, int n_in,
                              void* d_out, int out_size, void* d_ws, size_t ws_size,
                              hipStream_t stream) {
  const float* feat = (const float*)d_in[0];
  char* ws = (char*)d_ws;
  __hip_bfloat16* f = (__hip_bfloat16*)ws;                         // 8 MB
  float* psum = (float*)(ws + (size_t)NROW * DIM * 2);             // NB2*NROW floats (1 MB)
  float* ppos = psum + (size_t)NB2 * NROW;                         // 1 MB
  float* partial = ppos + (size_t)NB2 * NROW;                      // 64 floats
  float* out = (float*)d_out;

  normalize_kernel<<<NROW / 4, 256, 0, stream>>>(feat, f);
  pair_gram_kernel<<<NPAIR2, 512, 0, stream>>>(f, psum, ppos);
  loss_stage1<<<NROW / 128, 128, 0, stream>>>(psum, ppos, partial);
  loss_stage2<<<1, 64, 0, stream>>>(partial, out);
}

// Round 7
// 71.113 us; speedup vs baseline: 1.2820x; 1.2820x over previous
//
#include <hip/hip_runtime.h>
#include <hip/hip_bf16.h>

typedef __attribute__((ext_vector_type(8))) short short8;
typedef __attribute__((ext_vector_type(4))) float f32x4;

#define NROW 8192
#define DIM 512
#define BHALF 4096
#define NB 64            // number of 128-row blocks
#define BM 128
#define BK 64            // 128-B LDS rows + XOR swizzle -> measured 0 bank conflicts
#define NPAIR 2080       // NB*(NB+1)/2
#define XCHUNK 260       // 2080/8

__device__ __forceinline__ void gload_lds16(const void* g, void* l) {
  __builtin_amdgcn_global_load_lds(
      (const __attribute__((address_space(1))) void*)g,
      (__attribute__((address_space(3))) void*)l,
      16, 0, 0);
}

// ---------------- Kernel 1: row L2-normalize fp32 -> bf16 (wave per row) ----------------
__global__ __launch_bounds__(256) void normalize_kernel(const float* __restrict__ in,
                                                        __hip_bfloat16* __restrict__ out) {
  const int w = threadIdx.x >> 6, lane = threadIdx.x & 63;
  const int row = blockIdx.x * 4 + w;
  const float4* src = (const float4*)(in + (size_t)row * DIM) + lane * 2;
  const float4 v0 = src[0], v1 = src[1];
  float ss = v0.x * v0.x + v0.y * v0.y + v0.z * v0.z + v0.w * v0.w
           + v1.x * v1.x + v1.y * v1.y + v1.z * v1.z + v1.w * v1.w;
  #pragma unroll
  for (int m = 1; m < 64; m <<= 1) ss += __shfl_xor(ss, m);
  const float inv = 1.0f / fmaxf(sqrtf(ss), 1e-12f);
  __hip_bfloat16 o[8];
  o[0] = __float2bfloat16(v0.x * inv); o[1] = __float2bfloat16(v0.y * inv);
  o[2] = __float2bfloat16(v0.z * inv); o[3] = __float2bfloat16(v0.w * inv);
  o[4] = __float2bfloat16(v1.x * inv); o[5] = __float2bfloat16(v1.y * inv);
  o[6] = __float2bfloat16(v1.z * inv); o[7] = __float2bfloat16(v1.w * inv);
  *(short8*)(out + (size_t)row * DIM + lane * 8) = *(const short8*)o;
}

// ---------------- Kernel 2: symmetric 128x128 pair-tile Gram + exp-sums ----------------
// m97 regime: 2080 blocks (one per ib<=jb pair), 256 threads = 4 waves (2x2),
// 4x4 frags of 16x16x32 each. BK=64, SINGLE-buffer 32 KB LDS, 2-barrier K-loop
// (8 steps). ~3 blocks/CU co-resident hide each other's stage/drain stalls.
// LDS swizzle (r5-proven, 0 conflicts): slot s of row r holds global col16
// s^(r&7); staged via inverse-permuted global source (linear gload_lds dest).
__global__ __launch_bounds__(256, 3) void pair_gram_kernel(const __hip_bfloat16* __restrict__ f,
                                                           float* __restrict__ psum,
                                                           float* __restrict__ ppos) {
  __shared__ __align__(16) char lds[32768];   // A[128][64] @0, B[128][64] @16384

  // --- XCD swizzle + 16x16 macro-tiled triangular pair decode (scalar-uniform) ---
  const int bid = blockIdx.x;
  const int wg = (bid & 7) * XCHUNK + (bid >> 3);
  int rem = wg, MI = 0, MJ = 0;
  {
    bool brk = false;
    for (MI = 0; MI < 4 && !brk; ++MI) {
      for (MJ = MI; MJ < 4; ++MJ) {
        const int sz = (MI == MJ) ? 136 : 256;
        if (rem < sz) { brk = true; break; }
        rem -= sz;
      }
    }
    if (brk) --MI;
  }
  int ib, jb;
  if (MI == MJ) {          // 16x16 triangle: 136 entries
    int i = 0, b = 0;
    while (b + (16 - i) <= rem) { b += 16 - i; ++i; }
    ib = MI * 16 + i; jb = MI * 16 + i + (rem - b);
  } else {
    ib = MI * 16 + (rem >> 4); jb = MJ * 16 + (rem & 15);
  }

  const int tid = threadIdx.x;
  const int lane = tid & 63;
  const int w = tid >> 6;            // wave 0..3
  const int wy = w >> 1;             // row half (0/1): rows wy*64..+64
  const int wx = w & 1;              // col half (0/1): cols wx*64..+64
  const int fr = lane & 15;          // fragment row/col index
  const int g = lane >> 4;           // k-group / C-row group

  // staging source (inverse-swizzled): lane covers row w*8+(lane>>3) (+q*32),
  // global col16 (lane&7)^((lane>>3)&7); LDS dest linear (base + lane*16).
  const int srow8 = lane >> 3;
  const int scol = (lane & 7) ^ srow8;
  const __hip_bfloat16* gA = f + (size_t)(ib * BM + w * 8 + srow8) * DIM + scol * 8;
  const __hip_bfloat16* gB = f + (size_t)(jb * BM + w * 8 + srow8) * DIM + scol * 8;
  char* dA = lds + w * 1024;          // + q*4096
  char* dB = lds + 16384 + w * 1024;  // + q*4096

  f32x4 acc[4][4];
  const f32x4 zero = {0.f, 0.f, 0.f, 0.f};
  #pragma unroll
  for (int mi = 0; mi < 4; ++mi)
    #pragma unroll
    for (int ni = 0; ni < 4; ++ni) acc[mi][ni] = zero;

  // read-side swizzled 16B-slot offsets: sk(kk) = ((kk*4+g) ^ (fr&7)) * 16
  const int f7 = fr & 7;
  const int sk0 = ((0 + g) ^ f7) * 16;
  const int sk1 = ((4 + g) ^ f7) * 16;
  const int arow = (wy * 64 + fr) * 128;          // + mi*16*128
  const int brow = 16384 + (wx * 64 + fr) * 128;  // + ni*16*128

  for (int t = 0; t < 8; ++t) {
    __syncthreads();                  // previous tile's ds_reads complete
    const int k0 = t * BK;
    #pragma unroll
    for (int q = 0; q < 4; ++q) {
      gload_lds16(gA + k0 + (size_t)q * 32 * DIM, dA + q * 4096);
      gload_lds16(gB + k0 + (size_t)q * 32 * DIM, dB + q * 4096);
    }
    __syncthreads();                  // vmcnt(0) drain: tile staged

    #pragma unroll
    for (int kk = 0; kk < 2; ++kk) {
      const int sk = kk ? sk1 : sk0;
      short8 aF[4], bF[4];
      #pragma unroll
      for (int mi = 0; mi < 4; ++mi) aF[mi] = *(const short8*)(lds + arow + mi * 2048 + sk);
      #pragma unroll
      for (int ni = 0; ni < 4; ++ni) bF[ni] = *(const short8*)(lds + brow + ni * 2048 + sk);
      __builtin_amdgcn_s_setprio(1);
      #pragma unroll
      for (int mi = 0; mi < 4; ++mi)
        #pragma unroll
        for (int ni = 0; ni < 4; ++ni)
          acc[mi][ni] = __builtin_amdgcn_mfma_f32_16x16x32_bf16(aF[mi], bF[ni], acc[mi][ni], 0, 0, 0);
      __builtin_amdgcn_s_setprio(0);
    }
  }

  // ---- epilogue: exp, row-sums (rows of ib) + col-sums (rows of jb), pos-pair ----
  float rsum[4][4], prow[4][4], csum[4], pcol[4];
  #pragma unroll
  for (int mi = 0; mi < 4; ++mi)
    #pragma unroll
    for (int r = 0; r < 4; ++r) { rsum[mi][r] = 0.f; prow[mi][r] = 0.f; }
  #pragma unroll
  for (int ni = 0; ni < 4; ++ni) { csum[ni] = 0.f; pcol[ni] = 0.f; }

  #pragma unroll
  for (int mi = 0; mi < 4; ++mi) {
    #pragma unroll
    for (int ni = 0; ni < 4; ++ni) {
      const int gcol = jb * BM + wx * 64 + ni * 16 + fr;
      #pragma unroll
      for (int r = 0; r < 4; ++r) {
        const int grow = ib * BM + wy * 64 + mi * 16 + g * 4 + r;
        const float dot = acc[mi][ni][r];
        const float e = (gcol == grow) ? 0.f : __expf((dot - 1.0f) * 10.0f);
        const float pos = (gcol == (grow ^ BHALF)) ? dot : 0.f;
        rsum[mi][r] += e;  prow[mi][r] += pos;
        csum[ni] += e;     pcol[ni] += pos;
      }
    }
  }

  // row side: reduce over fr (lane bits 0..3)
  #pragma unroll
  for (int mi = 0; mi < 4; ++mi)
    #pragma unroll
    for (int r = 0; r < 4; ++r) {
      float a = rsum[mi][r], b = prow[mi][r];
      #pragma unroll
      for (int msk = 1; msk < 16; msk <<= 1) { a += __shfl_xor(a, msk); b += __shfl_xor(b, msk); }
      rsum[mi][r] = a; prow[mi][r] = b;
    }
  // col side: reduce over g (lane bits 4..5)
  #pragma unroll
  for (int ni = 0; ni < 4; ++ni) {
    float a = csum[ni], b = pcol[ni];
    a += __shfl_xor(a, 16); b += __shfl_xor(b, 16);
    a += __shfl_xor(a, 32); b += __shfl_xor(b, 32);
    csum[ni] = a; pcol[ni] = b;
  }

  // cross-wave combine via LDS (aliases tile buffer; safe after barrier)
  __syncthreads();
  float* sc = (float*)lds;  // rS[wx][128]@0, rP@256, cS[wy][128]@512, cP@768 (floats)
  if (fr == 0) {
    #pragma unroll
    for (int mi = 0; mi < 4; ++mi)
      #pragma unroll
      for (int r = 0; r < 4; ++r) {
        const int row = wy * 64 + mi * 16 + g * 4 + r;
        sc[wx * 128 + row]       = rsum[mi][r];
        sc[256 + wx * 128 + row] = prow[mi][r];
      }
  }
  if (g == 0) {
    #pragma unroll
    for (int ni = 0; ni < 4; ++ni) {
      const int col = wx * 64 + ni * 16 + fr;
      sc[512 + wy * 128 + col] = csum[ni];
      sc[768 + wy * 128 + col] = pcol[ni];
    }
  }
  __syncthreads();

  if (tid < 128) {                     // rows of block ib -> slot jb
    const int row = tid;
    const float s = sc[row] + sc[128 + row];
    const float p = sc[256 + row] + sc[384 + row];
    psum[(size_t)jb * NROW + ib * BM + row] = s;
    ppos[(size_t)jb * NROW + ib * BM + row] = p;
  } else if (ib != jb) {               // rows of block jb -> slot ib (transpose side)
    const int col = tid - 128;
    const float s = sc[512 + col] + sc[640 + col];
    const float p = sc[768 + col] + sc[896 + col];
    psum[(size_t)ib * NROW + jb * BM + col] = s;
    ppos[(size_t)ib * NROW + jb * BM + col] = p;
  }
}

// ---------------- Kernel 3a: per-row loss, 64 partials ----------------
__global__ __launch_bounds__(128) void loss_stage1(const float* __restrict__ psum,
                                                   const float* __restrict__ ppos,
                                                   float* __restrict__ partial) {
  const int row = blockIdx.x * 128 + threadIdx.x;
  float s = 0.f, p = 0.f;
  #pragma unroll 8
  for (int sl = 0; sl < NB; ++sl) {
    s += psum[(size_t)sl * NROW + row];
    p += ppos[(size_t)sl * NROW + row];
  }
  float local = logf(s) + 10.0f - 10.0f * p;
  #pragma unroll
  for (int m = 1; m < 64; m <<= 1) local += __shfl_xor(local, m);
  __shared__ float red[2];
  if ((threadIdx.x & 63) == 0) red[threadIdx.x >> 6] = local;
  __syncthreads();
  if (threadIdx.x == 0) partial[blockIdx.x] = red[0] + red[1];
}

// ---------------- Kernel 3b: final scalar ----------------
__global__ __launch_bounds__(64) void loss_stage2(const float* __restrict__ partial,
                                                  float* __restrict__ out) {
  float v = partial[threadIdx.x];
  #pragma unroll
  for (int m = 1; m < 64; m <<= 1) v += __shfl_xor(v, m);
  if (threadIdx.x == 0) out[0] = v * (1.0f / (float)BHALF);
}

extern "C" void kernel_launch(void* const* d_in, const int* in_sizes, int n_in,
                              void* d_out, int out_size, void* d_ws, size_t ws_size,
                              hipStream_t stream) {
  const float* feat = (const float*)d_in[0];
  char* ws = (char*)d_ws;
  __hip_bfloat16* f = (__hip_bfloat16*)ws;                         // 8 MB
  float* psum = (float*)(ws + (size_t)NROW * DIM * 2);             // NB*NROW floats (2 MB)
  float* ppos = psum + (size_t)NB * NROW;                          // 2 MB
  float* partial = ppos + (size_t)NB * NROW;                       // 64 floats
  float* out = (float*)d_out;

  normalize_kernel<<<NROW / 4, 256, 0, stream>>>(feat, f);
  pair_gram_kernel<<<NPAIR, 256, 0, stream>>>(f, psum, ppos);
  loss_stage1<<<NROW / 128, 128, 0, stream>>>(psum, ppos, partial);
  loss_stage2<<<1, 64, 0, stream>>>(partial, out);
}